// Round 6
// baseline (332.207 us; speedup 1.0000x reference)
//
#include <hip/hip_runtime.h>
#include <hip/hip_bf16.h>

typedef unsigned short u16;
typedef __attribute__((ext_vector_type(8))) short bf16x8;  // 8 bf16 = 4 VGPRs
typedef __attribute__((ext_vector_type(4))) float f32x4;

#define NH   32
#define HD   128
#define SEQ  2048
#define BQ   64
#define BK   64

// Vt swizzle: phys = d*64 + (((j>>3) ^ (d&7) ^ ((d>>3)&7))<<3) + (j&7)
__device__ __forceinline__ int vt_key(int d) { return (d & 7) ^ ((d >> 3) & 7); }

__device__ __forceinline__ u16 f2b(float x) {
  __hip_bfloat16 hb = __float2bfloat16(x);
  return *(u16*)&hb;
}

// load 8 fp32 (32B), convert to bf16x8
__device__ __forceinline__ bf16x8 cvt8(const float* src) {
  float4 a = *(const float4*)(src);
  float4 b = *(const float4*)(src + 4);
  u16 t[8];
  t[0] = f2b(a.x); t[1] = f2b(a.y); t[2] = f2b(a.z); t[3] = f2b(a.w);
  t[4] = f2b(b.x); t[5] = f2b(b.y); t[6] = f2b(b.z); t[7] = f2b(b.w);
  return *(bf16x8*)t;
}

// scaled variant (folds softmax scale * log2e into Q)
__device__ __forceinline__ bf16x8 cvt8s(const float* src, float sc) {
  float4 a = *(const float4*)(src);
  float4 b = *(const float4*)(src + 4);
  u16 t[8];
  t[0] = f2b(a.x * sc); t[1] = f2b(a.y * sc); t[2] = f2b(a.z * sc); t[3] = f2b(a.w * sc);
  t[4] = f2b(b.x * sc); t[5] = f2b(b.y * sc); t[6] = f2b(b.z * sc); t[7] = f2b(b.w * sc);
  return *(bf16x8*)t;
}

// fp32 K,V -> bf16 copies in workspace (each thread: 8 elems)
__global__ __launch_bounds__(256)
void cvt_bf16(const float* __restrict__ K, const float* __restrict__ V,
              u16* __restrict__ Kb, u16* __restrict__ Vb) {
  const size_t n8 = (size_t)SEQ * NH * HD / 8;
  size_t i = (size_t)blockIdx.x * 256 + threadIdx.x;
  const float* s; u16* d;
  if (i < n8) { s = K + i * 8;        d = Kb + i * 8; }
  else        { s = V + (i - n8) * 8; d = Vb + (i - n8) * 8; }
  bf16x8 v = cvt8(s);
  *(uint4*)d = *(uint4*)&v;
}

template <bool PRE>
__global__ __launch_bounds__(256, 3)
void attn_roco(const float* __restrict__ Qg, const float* __restrict__ Kg,
               const float* __restrict__ Vg, const u16* __restrict__ Kb,
               const u16* __restrict__ Vb, float* __restrict__ Og,
               float* __restrict__ ws) {
  __shared__ __align__(16) u16 Ks[BK * 128];   // XOR-swizzled: grp ^ (row&15)
  __shared__ __align__(16) u16 Vt[HD * BK];    // transposed + XOR-swizzled
  __shared__ __align__(16) u16 Ps[BQ * 64];    // XOR-swizzled: grp ^ (row&7)

  const int tid = threadIdx.x;
  const int wv  = tid >> 6;
  const int ln  = tid & 63;
  const int qd  = ln >> 4;   // quad
  const int cc  = ln & 15;

  const int h = (int)blockIdx.x & 31;
  // serpentine schedule: per-CU tile-work sums to a constant under RR dispatch.
  const int pos = ((int)blockIdx.x >> 5) & 7;
  const int grp = (int)blockIdx.x >> 8;
  int qt;
  if      (grp == 0) qt = 31 - pos;
  else if (grp == 1) qt = 16 + pos;
  else if (grp == 2) qt = 15 - pos;
  else               qt = pos;

  const int qbase  = qt * BQ;
  const int ntiles = qt + 1;

  // staging coords (per thread, reused every tile)
  const int srow = tid >> 4;          // 0..15 (+16 per it)
  const int sg   = tid & 15;          // 16B group
  const int sd0  = (tid & 15) << 3;   // V: d-range base

  // ---- Q tile into registers, pre-scaled by beta*log2e ----
  const float qsc = 0.08838834764831845f * 1.4426950408889634f;
  bf16x8 qf[4];
  {
    const float* qp = Qg + ((size_t)(qbase + wv * 16 + cc) * NH + h) * HD;
    #pragma unroll
    for (int kd = 0; kd < 4; ++kd)
      qf[kd] = cvt8s(qp + kd * 32 + qd * 8, qsc);
  }

  const int rbase = wv * 16 + qd * 4;

  float ls[4] = {0.f, 0.f, 0.f, 0.f};
  uint4 kpre[4];

  // ---- prefetch K tile 0 ----
  #pragma unroll
  for (int it = 0; it < 4; ++it) {
    const size_t off = ((size_t)(0 * BK + srow + it * 16) * NH + h) * HD + (sg << 3);
    if (PRE) kpre[it] = *(const uint4*)(Kb + off);
    else { bf16x8 kv = cvt8(Kg + off); kpre[it] = *(uint4*)&kv; }
  }

  // ================= PASS A: row sumexp (no max — scores bounded) =========
  for (int t = 0; t < ntiles; ++t) {
    __syncthreads();                       // WAR: prev compute done
    #pragma unroll
    for (int it = 0; it < 4; ++it) {
      int row = srow + it * 16;
      *(uint4*)(Ks + row * 128 + ((sg ^ (row & 15)) << 3)) = kpre[it];
    }
    __syncthreads();                       // staging visible
    if (t + 1 < ntiles) {
      #pragma unroll
      for (int it = 0; it < 4; ++it) {
        const size_t off = ((size_t)((t + 1) * BK + srow + it * 16) * NH + h) * HD + (sg << 3);
        if (PRE) kpre[it] = *(const uint4*)(Kb + off);
        else { bf16x8 kv = cvt8(Kg + off); kpre[it] = *(uint4*)&kv; }
      }
    }

    f32x4 S[4];
    #pragma unroll
    for (int f = 0; f < 4; ++f)
      #pragma unroll
      for (int r = 0; r < 4; ++r) S[f][r] = 0.f;

    #pragma unroll
    for (int kd = 0; kd < 4; ++kd) {
      #pragma unroll
      for (int f = 0; f < 4; ++f) {
        bf16x8 b = *(const bf16x8*)(Ks + (f * 16 + cc) * 128 +
                                    (((kd * 4 + qd) ^ cc) << 3));
        S[f] = __builtin_amdgcn_mfma_f32_16x16x32_bf16(qf[kd], b, S[f], 0, 0, 0);
      }
    }

    const bool diag = (t == qt);
    #pragma unroll
    for (int r = 0; r < 4; ++r) {
      const int iloc = rbase + r;
      float acc = 0.f;
      #pragma unroll
      for (int f = 0; f < 4; ++f) {
        float e = __builtin_amdgcn_exp2f(S[f][r]);
        if (diag && (f * 16 + cc) > iloc) e = 0.f;
        acc += e;
      }
      ls[r] += acc;
    }
  }

  // ---- prefetch pass-B tile 0 (overlaps the reduce below) ----
  uint4 vpre[4];
  #pragma unroll
  for (int it = 0; it < 4; ++it) {
    const size_t koff = ((size_t)(srow + it * 16) * NH + h) * HD + (sg << 3);
    if (PRE) { kpre[it] = *(const uint4*)(Kb + koff);
               vpre[it] = *(const uint4*)(Vb + koff); }
    else { bf16x8 kv = cvt8(Kg + koff); kpre[it] = *(uint4*)&kv;
           bf16x8 vv = cvt8(Vg + koff); vpre[it] = *(uint4*)&vv; }
  }

  // ---- one-shot row reduce ----
  float invl[4];
  #pragma unroll
  for (int r = 0; r < 4; ++r) {
    #pragma unroll
    for (int off = 1; off < 16; off <<= 1)
      ls[r] += __shfl_xor(ls[r], off);
    invl[r] = 1.f / ls[r];
  }

  f32x4 O[8];
  #pragma unroll
  for (int f = 0; f < 8; ++f)
    #pragma unroll
    for (int r = 0; r < 4; ++r) O[f][r] = 0.f;

  float* ws_s = ws + (size_t)h * SEQ;
  float* ws_q = ws + (size_t)NH * SEQ + (size_t)h * SEQ;

  // ================= PASS B: exact P, O += P*V, column sums =================
  for (int t = 0; t < ntiles; ++t) {
    __syncthreads();                       // WAR
    #pragma unroll
    for (int it = 0; it < 4; ++it) {
      int row = srow + it * 16;
      *(uint4*)(Ks + row * 128 + ((sg ^ (row & 15)) << 3)) = kpre[it];
    }
    #pragma unroll
    for (int it = 0; it < 4; ++it) {
      int j = srow + it * 16;
      u16 ev[8];
      *(uint4*)ev = vpre[it];
      #pragma unroll
      for (int e = 0; e < 8; ++e) {
        int d = sd0 + e;
        Vt[d * BK + ((((j >> 3) ^ vt_key(d)) << 3)) + (j & 7)] = ev[e];
      }
    }
    __syncthreads();                       // staging visible
    if (t + 1 < ntiles) {
      #pragma unroll
      for (int it = 0; it < 4; ++it) {
        const size_t off = ((size_t)((t + 1) * BK + srow + it * 16) * NH + h) * HD + (sg << 3);
        if (PRE) { kpre[it] = *(const uint4*)(Kb + off);
                   vpre[it] = *(const uint4*)(Vb + off); }
        else { bf16x8 kv = cvt8(Kg + off); kpre[it] = *(uint4*)&kv;
               bf16x8 vv = cvt8(Vg + off); vpre[it] = *(uint4*)&vv; }
      }
    }

    f32x4 S[4];
    #pragma unroll
    for (int f = 0; f < 4; ++f)
      #pragma unroll
      for (int r = 0; r < 4; ++r) S[f][r] = 0.f;

    #pragma unroll
    for (int kd = 0; kd < 4; ++kd) {
      #pragma unroll
      for (int f = 0; f < 4; ++f) {
        bf16x8 b = *(const bf16x8*)(Ks + (f * 16 + cc) * 128 +
                                    (((kd * 4 + qd) ^ cc) << 3));
        S[f] = __builtin_amdgcn_mfma_f32_16x16x32_bf16(qf[kd], b, S[f], 0, 0, 0);
      }
    }

    const bool diag = (t == qt);
    float cs[4] = {0.f, 0.f, 0.f, 0.f}, cq[4] = {0.f, 0.f, 0.f, 0.f};
    #pragma unroll
    for (int r = 0; r < 4; ++r) {
      const int iloc = rbase + r;
      const int prow = wv * 16 + qd * 4 + r;
      #pragma unroll
      for (int f = 0; f < 4; ++f) {
        float p = __builtin_amdgcn_exp2f(S[f][r]) * invl[r];
        if (diag && (f * 16 + cc) > iloc) p = 0.f;
        cs[f] += p;
        cq[f] += p * p;
        int pg = f * 2 + (cc >> 3);
        Ps[prow * 64 + ((pg ^ (prow & 7)) << 3) + (cc & 7)] = f2b(p);
      }
    }
    // column sums: combine quads, one atomic per column per wave
    #pragma unroll
    for (int f = 0; f < 4; ++f) {
      cs[f] += __shfl_xor(cs[f], 16); cs[f] += __shfl_xor(cs[f], 32);
      cq[f] += __shfl_xor(cq[f], 16); cq[f] += __shfl_xor(cq[f], 32);
      if (qd == f) {
        int j = t * BK + f * 16 + cc;
        atomicAdd(ws_s + j, cs[f]);
        atomicAdd(ws_q + j, cq[f]);
      }
    }
    // PV: O[16 x 128] += P[16 x 64] * V[64 x 128]  (Ps rows wave-private)
    #pragma unroll
    for (int ks = 0; ks < 2; ++ks) {
      bf16x8 a = *(const bf16x8*)(Ps + (wv * 16 + cc) * 64 +
                                  (((ks * 4 + qd) ^ (cc & 7)) << 3));
      #pragma unroll
      for (int f2 = 0; f2 < 8; ++f2) {
        int d = f2 * 16 + cc;
        int jb = ks * 4 + qd;
        bf16x8 b = *(const bf16x8*)(Vt + d * BK + ((jb ^ vt_key(d)) << 3));
        O[f2] = __builtin_amdgcn_mfma_f32_16x16x32_bf16(a, b, O[f2], 0, 0, 0);
      }
    }
  }

  // ---- epilogue: O already normalized (invl folded into P), fp32 out ----
  #pragma unroll
  for (int f2 = 0; f2 < 8; ++f2) {
    #pragma unroll
    for (int r = 0; r < 4; ++r) {
      int i = qbase + rbase + r;
      int d = f2 * 16 + cc;
      Og[((size_t)i * NH + h) * HD + d] = O[f2][r];
    }
  }
}

__global__ void roco_fin(const float* __restrict__ ws, float* __restrict__ out) {
  int i = (int)blockIdx.x * 256 + (int)threadIdx.x;  // 2*NH*SEQ total
  out[i] = ws[i];
}

extern "C" void kernel_launch(void* const* d_in, const int* in_sizes, int n_in,
                              void* d_out, int out_size, void* d_ws, size_t ws_size,
                              hipStream_t stream) {
  (void)in_sizes; (void)n_in; (void)out_size;
  const float* Qg = (const float*)d_in[0];
  const float* Kg = (const float*)d_in[1];
  const float* Vg = (const float*)d_in[2];
  float* Og = (float*)d_out;
  float* ws = (float*)d_ws;

  const size_t roco_elems = (size_t)2 * NH * SEQ;
  const size_t tens = (size_t)SEQ * NH * HD;
  const size_t need = roco_elems * 4 + 2 * tens * 2;
  const bool pre = ws_size >= need;

  (void)hipMemsetAsync(d_ws, 0, roco_elems * sizeof(float), stream);

  u16* Kb = (u16*)(ws + roco_elems);
  u16* Vb = Kb + tens;

  if (pre) {
    cvt_bf16<<<dim3((unsigned)(2 * tens / 8 / 256)), dim3(256), 0, stream>>>(
        Kg, Vg, Kb, Vb);
    attn_roco<true><<<dim3(NH * (SEQ / BQ)), dim3(256), 0, stream>>>(
        Qg, Kg, Vg, Kb, Vb, Og, ws);
  } else {
    attn_roco<false><<<dim3(NH * (SEQ / BQ)), dim3(256), 0, stream>>>(
        Qg, Kg, Vg, Kb, Vb, Og, ws);
  }

  roco_fin<<<dim3((2 * NH * SEQ) / 256), dim3(256), 0, stream>>>(
      ws, Og + tens);
}

// Round 7
// 226.633 us; speedup vs baseline: 1.4658x; 1.4658x over previous
//
#include <hip/hip_runtime.h>
#include <hip/hip_bf16.h>

typedef unsigned short u16;
typedef __attribute__((ext_vector_type(8))) short bf16x8;  // 8 bf16 = 4 VGPRs
typedef __attribute__((ext_vector_type(4))) float f32x4;

#define NH   32
#define HD   128
#define SEQ  2048
#define BQ   64
#define BK   64

// Vt swizzle key: phys group p = g ^ vt_key(d) within a d-row of 8 groups
__device__ __forceinline__ int vt_key(int d) { return (d & 7) ^ ((d >> 3) & 7); }

__device__ __forceinline__ u16 f2b(float x) {
  __hip_bfloat16 hb = __float2bfloat16(x);
  return *(u16*)&hb;
}

// load 8 fp32 (32B), convert to bf16x8
__device__ __forceinline__ bf16x8 cvt8(const float* src) {
  float4 a = *(const float4*)(src);
  float4 b = *(const float4*)(src + 4);
  u16 t[8];
  t[0] = f2b(a.x); t[1] = f2b(a.y); t[2] = f2b(a.z); t[3] = f2b(a.w);
  t[4] = f2b(b.x); t[5] = f2b(b.y); t[6] = f2b(b.z); t[7] = f2b(b.w);
  return *(bf16x8*)t;
}

__device__ __forceinline__ bf16x8 cvt8s(const float* src, float sc) {
  float4 a = *(const float4*)(src);
  float4 b = *(const float4*)(src + 4);
  u16 t[8];
  t[0] = f2b(a.x * sc); t[1] = f2b(a.y * sc); t[2] = f2b(a.z * sc); t[3] = f2b(a.w * sc);
  t[4] = f2b(b.x * sc); t[5] = f2b(b.y * sc); t[6] = f2b(b.z * sc); t[7] = f2b(b.w * sc);
  return *(bf16x8*)t;
}

// async global->LDS, 16B per lane; LDS dst must be wave-base + lane*16
__device__ __forceinline__ void dma16(const u16* g, u16* l) {
  __builtin_amdgcn_global_load_lds(
      (const __attribute__((address_space(1))) void*)g,
      (__attribute__((address_space(3))) void*)l, 16, 0, 0);
}

// prep: Kb = bf16(K) same layout [j][h][d]; Vtb = bf16(V) transposed [h][d][j]
__global__ __launch_bounds__(256)
void prep(const float* __restrict__ K, const float* __restrict__ V,
          u16* __restrict__ Kb, u16* __restrict__ Vtb) {
  __shared__ __align__(16) u16 T[64 * 136];
  int b = (int)blockIdx.x;
  int tid = (int)threadIdx.x;
  if (b < 4096) {                       // K: 4096*256*8 = SEQ*NH*HD elems
    size_t i = (size_t)b * 256 + tid;
    bf16x8 v = cvt8(K + i * 8);
    *(uint4*)(Kb + i * 8) = *(uint4*)&v;
  } else {                              // V transpose: 32 heads x 32 j-tiles
    b -= 4096;
    int h = b >> 5, jt = b & 31;
    #pragma unroll
    for (int it = 0; it < 4; ++it) {
      int c = tid + it * 256;           // [0,1024): j = c>>4, d0 = (c&15)*8
      int j = c >> 4, d0 = (c & 15) << 3;
      bf16x8 v = cvt8(V + ((size_t)(jt * 64 + j) * NH + h) * HD + d0);
      *(uint4*)(T + j * 136 + d0) = *(uint4*)&v;
    }
    __syncthreads();
    #pragma unroll
    for (int it = 0; it < 4; ++it) {
      int c = tid + it * 256;           // [0,1024): d = c>>3, jg = (c&7)*8
      int d = c >> 3, jg = (c & 7) << 3;
      u16 tmp[8];
      #pragma unroll
      for (int e = 0; e < 8; ++e) tmp[e] = T[(jg + e) * 136 + d];
      *(uint4*)(Vtb + ((size_t)h * HD + d) * SEQ + jt * 64 + jg) = *(uint4*)tmp;
    }
  }
}

template <bool PRE>
__global__ __launch_bounds__(256, 3)
void attn_roco(const float* __restrict__ Qg, const float* __restrict__ Kg,
               const float* __restrict__ Vg, const u16* __restrict__ Kb,
               const u16* __restrict__ Vtb, float* __restrict__ Og,
               float* __restrict__ ws) {
  // union: pass A (PRE) KsA 128x128 = 32KB  |  pass B Ks 16KB + Vt 16KB; + Ps 8KB
  __shared__ __align__(16) u16 smem[20480];   // 40960 B -> 3 blocks/CU
  u16* KsA = smem;            // pass A PRE: [row][phys-grp], linear, XOR in src
  u16* Ks  = smem;            // pass B: 64x128, phys grp = g ^ (row&15)
  u16* Vt  = smem + 8192;     // pass B: [d][64j], phys grp = g ^ vt_key(d)
  u16* Ps  = smem + 16384;    // 64x64, phys grp = pg ^ (prow&7)

  const int tid = threadIdx.x;
  const int wv  = tid >> 6;
  const int ln  = tid & 63;
  const int qd  = ln >> 4;
  const int cc  = ln & 15;

  const int h = (int)blockIdx.x & 31;
  // serpentine schedule: per-CU tile-work sums to a constant under RR dispatch
  const int pos = ((int)blockIdx.x >> 5) & 7;
  const int grp = (int)blockIdx.x >> 8;
  int qt;
  if      (grp == 0) qt = 31 - pos;
  else if (grp == 1) qt = 16 + pos;
  else if (grp == 2) qt = 15 - pos;
  else               qt = pos;

  const int qbase  = qt * BQ;
  const int ntiles = qt + 1;

  // ---- Q tile into registers, pre-scaled by beta*log2e ----
  const float qsc = 0.08838834764831845f * 1.4426950408889634f;
  bf16x8 qf[4];
  {
    const float* qp = Qg + ((size_t)(qbase + wv * 16 + cc) * NH + h) * HD;
    #pragma unroll
    for (int kd = 0; kd < 4; ++kd)
      qf[kd] = cvt8s(qp + kd * 32 + qd * 8, qsc);
  }

  const int rbase = wv * 16 + qd * 4;
  float ls[4] = {0.f, 0.f, 0.f, 0.f};

  // ================= PASS A: row sumexp (no max — scores bounded) =========
  if (PRE) {
    const int ntA = (qt >> 1) + 1;           // BK=128 tiles
    for (int ta = 0; ta < ntA; ++ta) {
      __syncthreads();                       // WAR on KsA
      #pragma unroll
      for (int it = 0; it < 8; ++it) {
        int c = it * 256 + tid;              // [0,2048): row = c>>4, p = c&15
        int row = c >> 4, g = (c & 15) ^ (row & 15);
        dma16(Kb + ((size_t)(ta * 128 + row) * NH + h) * HD + (g << 3),
              KsA + (size_t)c * 8);
      }
      __syncthreads();                       // DMA drained + visible

      f32x4 S[8];
      #pragma unroll
      for (int f = 0; f < 8; ++f)
        #pragma unroll
        for (int r = 0; r < 4; ++r) S[f][r] = 0.f;

      #pragma unroll
      for (int kd = 0; kd < 4; ++kd) {
        #pragma unroll
        for (int f = 0; f < 8; ++f) {
          bf16x8 b = *(const bf16x8*)(KsA + (f * 16 + cc) * 128 +
                                      (((kd * 4 + qd) ^ cc) << 3));
          S[f] = __builtin_amdgcn_mfma_f32_16x16x32_bf16(qf[kd], b, S[f], 0, 0, 0);
        }
      }

      const bool last = (ta == ntA - 1);
      #pragma unroll
      for (int r = 0; r < 4; ++r) {
        const int ig = qbase + rbase + r;
        float acc = 0.f;
        #pragma unroll
        for (int f = 0; f < 8; ++f) {
          float e = __builtin_amdgcn_exp2f(S[f][r]);
          if (last && (ta * 128 + f * 16 + cc) > ig) e = 0.f;
          acc += e;
        }
        ls[r] += acc;
      }
    }
  } else {
    for (int t = 0; t < ntiles; ++t) {
      __syncthreads();
      #pragma unroll
      for (int it = 0; it < 4; ++it) {
        int c = tid + it * 256;
        int row = c >> 4, g = c & 15;
        bf16x8 kv = cvt8(Kg + ((size_t)(t * BK + row) * NH + h) * HD + (g << 3));
        *(uint4*)(Ks + row * 128 + ((g ^ (row & 15)) << 3)) = *(uint4*)&kv;
      }
      __syncthreads();

      f32x4 S[4];
      #pragma unroll
      for (int f = 0; f < 4; ++f)
        #pragma unroll
        for (int r = 0; r < 4; ++r) S[f][r] = 0.f;

      #pragma unroll
      for (int kd = 0; kd < 4; ++kd) {
        #pragma unroll
        for (int f = 0; f < 4; ++f) {
          bf16x8 b = *(const bf16x8*)(Ks + (f * 16 + cc) * 128 +
                                      (((kd * 4 + qd) ^ cc) << 3));
          S[f] = __builtin_amdgcn_mfma_f32_16x16x32_bf16(qf[kd], b, S[f], 0, 0, 0);
        }
      }

      const bool diag = (t == qt);
      #pragma unroll
      for (int r = 0; r < 4; ++r) {
        const int iloc = rbase + r;
        float acc = 0.f;
        #pragma unroll
        for (int f = 0; f < 4; ++f) {
          float e = __builtin_amdgcn_exp2f(S[f][r]);
          if (diag && (f * 16 + cc) > iloc) e = 0.f;
          acc += e;
        }
        ls[r] += acc;
      }
    }
  }

  // ---- one-shot row reduce ----
  float invl[4];
  #pragma unroll
  for (int r = 0; r < 4; ++r) {
    #pragma unroll
    for (int off = 1; off < 16; off <<= 1)
      ls[r] += __shfl_xor(ls[r], off);
    invl[r] = 1.f / ls[r];
  }

  f32x4 O[8];
  #pragma unroll
  for (int f = 0; f < 8; ++f)
    #pragma unroll
    for (int r = 0; r < 4; ++r) O[f][r] = 0.f;

  float* ws_s = ws + (size_t)h * SEQ;
  float* ws_q = ws + (size_t)NH * SEQ + (size_t)h * SEQ;

  // ================= PASS B: exact P, O += P*V, column sums =================
  for (int t = 0; t < ntiles; ++t) {
    __syncthreads();                         // WAR
    if (PRE) {
      #pragma unroll
      for (int it = 0; it < 4; ++it) {
        int c = it * 256 + tid;              // [0,1024): K tile 64x128
        int row = c >> 4, g = (c & 15) ^ (row & 15);
        dma16(Kb + ((size_t)(t * BK + row) * NH + h) * HD + (g << 3),
              Ks + (size_t)c * 8);
      }
      #pragma unroll
      for (int it = 0; it < 4; ++it) {
        int c = it * 256 + tid;              // [0,1024): V tile [d][64j]
        int d = c >> 3, g = (c & 7) ^ vt_key(d);
        dma16(Vtb + ((size_t)h * HD + d) * SEQ + t * BK + (g << 3),
              Vt + (size_t)c * 8);
      }
    } else {
      #pragma unroll
      for (int it = 0; it < 4; ++it) {
        int c = tid + it * 256;
        int row = c >> 4, g = c & 15;
        bf16x8 kv = cvt8(Kg + ((size_t)(t * BK + row) * NH + h) * HD + (g << 3));
        *(uint4*)(Ks + row * 128 + ((g ^ (row & 15)) << 3)) = *(uint4*)&kv;
      }
      #pragma unroll
      for (int it = 0; it < 4; ++it) {
        int c = tid + it * 256;
        int j = c >> 4, d0 = (c & 15) << 3;
        bf16x8 v = cvt8(Vg + ((size_t)(t * BK + j) * NH + h) * HD + d0);
        u16 ev[8];
        *(uint4*)ev = *(uint4*)&v;
        #pragma unroll
        for (int e = 0; e < 8; ++e) {
          int d = d0 + e;
          Vt[d * BK + ((((j >> 3) ^ vt_key(d)) << 3)) + (j & 7)] = ev[e];
        }
      }
    }
    __syncthreads();                         // staging visible

    f32x4 S[4];
    #pragma unroll
    for (int f = 0; f < 4; ++f)
      #pragma unroll
      for (int r = 0; r < 4; ++r) S[f][r] = 0.f;

    #pragma unroll
    for (int kd = 0; kd < 4; ++kd) {
      #pragma unroll
      for (int f = 0; f < 4; ++f) {
        bf16x8 b = *(const bf16x8*)(Ks + (f * 16 + cc) * 128 +
                                    (((kd * 4 + qd) ^ cc) << 3));
        S[f] = __builtin_amdgcn_mfma_f32_16x16x32_bf16(qf[kd], b, S[f], 0, 0, 0);
      }
    }

    const bool diag = (t == qt);
    float cs[4] = {0.f, 0.f, 0.f, 0.f}, cq[4] = {0.f, 0.f, 0.f, 0.f};
    #pragma unroll
    for (int r = 0; r < 4; ++r) {
      const int iloc = rbase + r;
      const int prow = wv * 16 + qd * 4 + r;
      #pragma unroll
      for (int f = 0; f < 4; ++f) {
        float p = __builtin_amdgcn_exp2f(S[f][r]) * invl[r];
        if (diag && (f * 16 + cc) > iloc) p = 0.f;
        cs[f] += p;
        cq[f] += p * p;
        int pg = f * 2 + (cc >> 3);
        Ps[prow * 64 + ((pg ^ (prow & 7)) << 3) + (cc & 7)] = f2b(p);
      }
    }
    // column sums: combine quads, one atomic per column per wave
    #pragma unroll
    for (int f = 0; f < 4; ++f) {
      cs[f] += __shfl_xor(cs[f], 16); cs[f] += __shfl_xor(cs[f], 32);
      cq[f] += __shfl_xor(cq[f], 16); cq[f] += __shfl_xor(cq[f], 32);
      if (qd == f) {
        int j = t * BK + f * 16 + cc;
        atomicAdd(ws_s + j, cs[f]);
        atomicAdd(ws_q + j, cq[f]);
      }
    }
    // PV: O[16 x 128] += P[16 x 64] * V[64 x 128]
    #pragma unroll
    for (int ks = 0; ks < 2; ++ks) {
      bf16x8 a = *(const bf16x8*)(Ps + (wv * 16 + cc) * 64 +
                                  (((ks * 4 + qd) ^ (cc & 7)) << 3));
      #pragma unroll
      for (int f2 = 0; f2 < 8; ++f2) {
        int d = f2 * 16 + cc;
        int jb = ks * 4 + qd;
        bf16x8 b = *(const bf16x8*)(Vt + d * BK + ((jb ^ vt_key(d)) << 3));
        O[f2] = __builtin_amdgcn_mfma_f32_16x16x32_bf16(a, b, O[f2], 0, 0, 0);
      }
    }
  }

  // ---- epilogue: O already normalized (invl folded into P) ----
  #pragma unroll
  for (int f2 = 0; f2 < 8; ++f2) {
    #pragma unroll
    for (int r = 0; r < 4; ++r) {
      int i = qbase + rbase + r;
      int d = f2 * 16 + cc;
      Og[((size_t)i * NH + h) * HD + d] = O[f2][r];
    }
  }
}

__global__ void roco_fin(const float* __restrict__ ws, float* __restrict__ out) {
  int i = (int)blockIdx.x * 256 + (int)threadIdx.x;
  out[i] = ws[i];
}

extern "C" void kernel_launch(void* const* d_in, const int* in_sizes, int n_in,
                              void* d_out, int out_size, void* d_ws, size_t ws_size,
                              hipStream_t stream) {
  (void)in_sizes; (void)n_in; (void)out_size;
  const float* Qg = (const float*)d_in[0];
  const float* Kg = (const float*)d_in[1];
  const float* Vg = (const float*)d_in[2];
  float* Og = (float*)d_out;
  float* ws = (float*)d_ws;

  const size_t roco_elems = (size_t)2 * NH * SEQ;
  const size_t tens = (size_t)SEQ * NH * HD;
  const size_t need = roco_elems * 4 + 2 * tens * 2;
  const bool pre = ws_size >= need;

  (void)hipMemsetAsync(d_ws, 0, roco_elems * sizeof(float), stream);

  u16* Kb  = (u16*)(ws + roco_elems);
  u16* Vtb = Kb + tens;

  if (pre) {
    prep<<<dim3(4096 + 1024), dim3(256), 0, stream>>>(Kg, Vg, Kb, Vtb);
    attn_roco<true><<<dim3(NH * (SEQ / BQ)), dim3(256), 0, stream>>>(
        Qg, Kg, Vg, Kb, Vtb, Og, ws);
  } else {
    attn_roco<false><<<dim3(NH * (SEQ / BQ)), dim3(256), 0, stream>>>(
        Qg, Kg, Vg, Kb, Vtb, Og, ws);
  }

  roco_fin<<<dim3((2 * NH * SEQ) / 256), dim3(256), 0, stream>>>(
      ws, Og + tens);
}